// Round 18
// baseline (477.428 us; speedup 1.0000x reference)
//
#include <hip/hip_runtime.h>
#include <math.h>

#define N_PIX 16384
#define EMB 128
#define LN_EPS 1e-5f
#define INV_TEMP 10.0f
#define C2 14.4269504f          // INV_TEMP * log2(e): logits in log2 units
#define THR2 14.0f              // skip threshold (log2 units)
#define RTHR 8.0f               // cross-tier / defer-rescale threshold (log2 units)
#define BKT 32
#define NTILES (N_PIX / BKT)    // 512

typedef __attribute__((ext_vector_type(8))) short short8v;
typedef __attribute__((ext_vector_type(4))) float f32x4;

__device__ __forceinline__ float fexp2(float x) {
#if __has_builtin(__builtin_amdgcn_exp2f)
    return __builtin_amdgcn_exp2f(x);
#else
    float r; asm("v_exp_f32 %0, %1" : "=v"(r) : "v"(x)); return r;
#endif
}

__device__ __forceinline__ unsigned cvt_pk_bf16(float lo, float hi) {
    unsigned r;
    asm("v_cvt_pk_bf16_f32 %0, %1, %2" : "=v"(r) : "v"(lo), "v"(hi));
    return r;
}

__device__ __forceinline__ void split_bf16(float x, unsigned short& h, unsigned short& l) {
    union { float f; unsigned u; } a; a.f = x;
    h = (unsigned short)(a.u >> 16);
    union { unsigned u; float f; } b; b.u = a.u & 0xFFFF0000u;
    float r = x - b.f;
    union { float f; unsigned u; } c; c.f = r;
    unsigned ru = c.u + 0x7FFFu + ((c.u >> 16) & 1u);
    l = (unsigned short)(ru >> 16);
}

// ---------------------------------------------------------------------------
// Kernel 1: descriptor + MLP(6->128) + LN + MLP(128->128); emits bf16 hi/lo
// ---------------------------------------------------------------------------
__global__ __launch_bounds__(128) void encode_kernel(
    const float* __restrict__ ego_cls, const float* __restrict__ ego_reg,
    const float* __restrict__ other_cls, const float* __restrict__ other_reg,
    const float* __restrict__ w1, const float* __restrict__ b1,
    const float* __restrict__ ln_g, const float* __restrict__ ln_b,
    const float* __restrict__ w2, const float* __restrict__ b2,
    unsigned short* __restrict__ q_hi, unsigned short* __restrict__ q_lo,
    unsigned short* __restrict__ k_hi, unsigned short* __restrict__ k_lo)
{
    int r = blockIdx.x;
    const float* cls; const float* reg; unsigned short *ohi, *olo; int p;
    if (r < N_PIX) { cls = ego_cls;   reg = ego_reg;   ohi = q_hi; olo = q_lo; p = r; }
    else           { cls = other_cls; reg = other_reg; ohi = k_hi; olo = k_lo; p = r - N_PIX; }

    int j = threadIdx.x;

    float x0 = reg[3*N_PIX + p];
    float x1 = reg[4*N_PIX + p];
    float x2 = reg[5*N_PIX + p];
    float th = reg[6*N_PIX + p];
    float x3 = sinf(th);
    float x4 = cosf(th);
    float x5 = fmaxf(cls[p], cls[N_PIX + p]);

    float h = x0*w1[0*EMB+j] + x1*w1[1*EMB+j] + x2*w1[2*EMB+j]
            + x3*w1[3*EMB+j] + x4*w1[4*EMB+j] + x5*w1[5*EMB+j] + b1[j];
    h = fmaxf(h, 0.f);

    __shared__ float hn[EMB];
    __shared__ float red[4];

    float s = h, s2 = h*h;
    #pragma unroll
    for (int off = 32; off >= 1; off >>= 1) {
        s  += __shfl_xor(s,  off);
        s2 += __shfl_xor(s2, off);
    }
    int wid = j >> 6;
    if ((j & 63) == 0) { red[wid] = s; red[2+wid] = s2; }
    __syncthreads();
    float tot  = red[0] + red[1];
    float tot2 = red[2] + red[3];
    float mu  = tot * (1.f/EMB);
    float var = tot2 * (1.f/EMB) - mu*mu;
    float rstd = rsqrtf(var + LN_EPS);
    float hnj = (h - mu) * rstd * ln_g[j] + ln_b[j];
    hn[j] = hnj;
    __syncthreads();

    float acc = b2[j];
    #pragma unroll 8
    for (int k = 0; k < EMB; ++k)
        acc += hn[k] * w2[k*EMB + j];

    unsigned short hb, lb;
    split_bf16(acc, hb, lb);
    ohi[(size_t)p * EMB + j] = hb;
    olo[(size_t)p * EMB + j] = lb;
}

// ---------------------------------------------------------------------------
// Kernel 2: split-K flash attention, swapped-operand MFMA, 3-tier tile path.
// R18: HI PLANE ONLY in LDS (4 x 8KB buffers, 32KB/block -> 4 blocks/CU
// fully resident). Lo plane read direct from global (L2-resident slice)
// inside the rare cross tier only — per-lane frag map proven bit-exact in R9.
// Barrier skeleton + tier logic FROZEN from R17.
// ---------------------------------------------------------------------------
__device__ __forceinline__ void gl_lds16(const void* g, void* l) {
    __builtin_amdgcn_global_load_lds(
        (const __attribute__((address_space(1))) unsigned int*)(g),
        (__attribute__((address_space(3))) unsigned int*)(l), 16, 0, 0);
}

__global__ __launch_bounds__(512, 4) void attn_kernel(
    const unsigned short* __restrict__ Qhi, const unsigned short* __restrict__ Qlo,
    const unsigned short* __restrict__ Khi, const unsigned short* __restrict__ Klo,
    const float* __restrict__ other_cls, const float* __restrict__ other_reg,
    float* __restrict__ macc, float* __restrict__ mbuf, float* __restrict__ lbuf,
    float* __restrict__ out, int S, int TPS, int XPS, int direct)
{
    __shared__ char Ks[4 * 8192];   // [pair][sub][hi plane 8KB]

    const int tid  = threadIdx.x;
    const int w    = tid >> 6, lane = tid & 63;   // w in 0..7
    const int lg   = lane >> 4, lk = lane & 15;

    // XCD-grouped bijective decode: slice pinned per XCD (K-slice L2-resident)
    const int b  = blockIdx.x;
    const int s  = (b & 7) / XPS;
    const int qb = (b >> 3) * XPS + (b & 7) % XPS;   // 0..127
    const int qt0 = qb * 128 + w * 16;
    const int t0  = s * TPS;
    const int HTPS = TPS >> 1;       // pairs per slice

    // ---- Q B-operand frags (k-map: k = kk*32 + lg*8 + e) ----
    short8v qbh[4], qbl[4];
    {
        const unsigned short* qh = Qhi + (size_t)(qt0 + lk) * EMB + lg*8;
        const unsigned short* ql = Qlo + (size_t)(qt0 + lk) * EMB + lg*8;
        #pragma unroll
        for (int kk = 0; kk < 4; ++kk) {
            qbh[kk] = *(const short8v*)(qh + kk*32);
            qbl[kk] = *(const short8v*)(ql + kk*32);
        }
    }

    // ---- staging precompute (waves 0-3; hi plane only: 2 issues/tile) ----
    const bool stager = (w < 4);
    int st_row[2], st_scol[2], st_dst[2];
    #pragma unroll
    for (int i = 0; i < 2; ++i) {
        int cb = i*256 + (w & 3)*64 + lane;     // 16B-chunk idx in tile (0..511)
        int row  = cb >> 4;                     // key row 0..31
        int colb = (cb & 15) << 4;
        st_row[i] = row;
        st_scol[i] = colb ^ ((row & 7) << 4);   // inverse-swizzled source col
        st_dst[i] = i*4096 + (w & 3)*1024;      // + lane*16 (HW)
    }

    // ---- A-frag read offsets (bytes in hi plane; same XOR as write) ----
    int koff[4];
    #pragma unroll
    for (int kk = 0; kk < 4; ++kk)
        koff[kk] = (kk*64 + lg*16) ^ ((lk & 7) << 4);

    const float* vplane = (lk < 2) ? (other_cls + lk * N_PIX)
                                   : (other_reg + (lk - 2) * N_PIX);

    float mn = -INFINITY;      // softmax reference (log2 units), query-uniform
    float mtrack = -INFINITY;  // running query-uniform max for skip test
    float lrow = 0.f;          // PER-LANE partial (8 keys); reduced at end
    f32x4 accv = {0.f, 0.f, 0.f, 0.f};

    // prologue: stage pair 0 (tiles t0, t0+1) into buffers 0,1
    if (stager) {
        #pragma unroll
        for (int sub = 0; sub < 2; ++sub) {
            int kb0 = (t0 + sub) * BKT;
            #pragma unroll
            for (int i = 0; i < 2; ++i) {
                const char* g = (const char*)Khi + (((size_t)(kb0 + st_row[i])) << 8) + st_scol[i];
                gl_lds16(g, Ks + sub * 8192 + st_dst[i]);
            }
        }
    }

    int cur = 0;
    for (int it = 0; it < HTPS; ++it) {
        if (stager) {
            if (it + 1 < HTPS) {
                #pragma unroll
                for (int sub = 0; sub < 2; ++sub) {
                    int kn0 = (t0 + 2*(it+1) + sub) * BKT;
                    char* dstb = Ks + ((cur ^ 1) * 2 + sub) * 8192;
                    #pragma unroll
                    for (int i = 0; i < 2; ++i) {
                        const char* g = (const char*)Khi + (((size_t)(kn0 + st_row[i])) << 8) + st_scol[i];
                        gl_lds16(g, dstb + st_dst[i]);
                    }
                }
                asm volatile("s_waitcnt vmcnt(4)" ::: "memory");  // only next-pair stage outstanding
            } else {
                asm volatile("s_waitcnt vmcnt(0)" ::: "memory");
            }
        }
        __builtin_amdgcn_sched_barrier(0);
        __builtin_amdgcn_s_barrier();
        __builtin_amdgcn_sched_barrier(0);

        #pragma unroll
        for (int sub = 0; sub < 2; ++sub) {
            const int kb0 = (t0 + 2*it + sub) * BKT;
            const char* Bh = Ks + (cur * 2 + sub) * 8192;
            const int rowb = lk * 256;

            // ---- hi*hi pass: S[key][query]; keep hi A-frags in regs ----
            short8v ah0r[4], ah1r[4];
            f32x4 S0 = {0,0,0,0}, S1 = {0,0,0,0};
            #pragma unroll
            for (int kk = 0; kk < 4; ++kk) {
                ah0r[kk] = *(const short8v*)(Bh + rowb + koff[kk]);
                ah1r[kk] = *(const short8v*)(Bh + 4096 + rowb + koff[kk]);
            }
            __builtin_amdgcn_s_setprio(1);
            #pragma unroll
            for (int kk = 0; kk < 4; ++kk) {
                S0 = __builtin_amdgcn_mfma_f32_16x16x32_bf16(ah0r[kk], qbh[kk], S0, 0, 0, 0);
                S1 = __builtin_amdgcn_mfma_f32_16x16x32_bf16(ah1r[kk], qbh[kk], S1, 0, 0, 0);
            }
            __builtin_amdgcn_s_setprio(0);

            // ---- shuffle-free skip test (exact: __any spans all lanes) ----
            float mtl = fmaxf(fmaxf(fmaxf(S0[0], S0[1]), fmaxf(S0[2], S0[3])),
                              fmaxf(fmaxf(S1[0], S1[1]), fmaxf(S1[2], S1[3])));
            float mtl2 = mtl * C2;
            if (__any(mtl2 > mtrack - THR2)) {
                // V loads (taken tiles only; use-drained before barrier)
                float vt[8];
                #pragma unroll
                for (int e = 0; e < 8; ++e)
                    vt[e] = vplane[kb0 + 16*(e>>2) + lg*4 + (e&3)];

                // ---- tier test (shuffle-free, exact) ----
                float sc = 1.f;
                if (__any(mtl2 > mn - RTHR)) {
                    // query-uniform tile max (2 shuffles; cross tier only)
                    float mt = fmaxf(mtl, __shfl_xor(mtl, 16));
                    mt = fmaxf(mt, __shfl_xor(mt, 32));
                    float mt2 = mt * C2;
                    mtrack = fmaxf(mtrack, mt2);

                    // lo-plane A-frags direct from global (R9-proven map)
                    const unsigned short* lo0 = Klo + (size_t)(kb0 + lk) * EMB + lg*8;
                    const unsigned short* lo1 = Klo + (size_t)(kb0 + 16 + lk) * EMB + lg*8;

                    // ---- cross terms: + kh*ql + kl*qh (hi frags from regs) ----
                    __builtin_amdgcn_s_setprio(1);
                    #pragma unroll
                    for (int kk = 0; kk < 4; ++kk) {
                        short8v al0 = *(const short8v*)(lo0 + kk*32);
                        short8v al1 = *(const short8v*)(lo1 + kk*32);
                        S0 = __builtin_amdgcn_mfma_f32_16x16x32_bf16(ah0r[kk], qbl[kk], S0, 0, 0, 0);
                        S1 = __builtin_amdgcn_mfma_f32_16x16x32_bf16(ah1r[kk], qbl[kk], S1, 0, 0, 0);
                        S0 = __builtin_amdgcn_mfma_f32_16x16x32_bf16(al0, qbh[kk], S0, 0, 0, 0);
                        S1 = __builtin_amdgcn_mfma_f32_16x16x32_bf16(al1, qbh[kk], S1, 0, 0, 0);
                    }
                    __builtin_amdgcn_s_setprio(0);

                    // ---- defer-rescale (mn query-uniform) ----
                    if (__any(mt2 > mn + RTHR)) {
                        float mnn = fmaxf(mn, mt2);
                        sc = fexp2(mn - mnn);           // first tile: exp2(-inf)=0
                        mn = mnn;
                        #pragma unroll
                        for (int r = 0; r < 4; ++r)
                            accv[r] *= __shfl(sc, lg*4 + r);
                    }
                }
                // mid tier: hi*hi logits only; all weights < 2^-RTHR -> error ~0

                // per-lane partial row-sum; lrow reduced across lanes at END
                float p[8]; float rs = 0.f;
                #pragma unroll
                for (int r = 0; r < 4; ++r) { p[r]   = fexp2(fmaf(S0[r], C2, -mn)); rs += p[r];   }
                #pragma unroll
                for (int r = 0; r < 4; ++r) { p[4+r] = fexp2(fmaf(S1[r], C2, -mn)); rs += p[4+r]; }
                lrow = lrow * sc + rs;

                // ---- PV: one MFMA; key-map pi(l,e)=16*(e>>2)+lg*4+(e&3) ----
                union { short8v v; unsigned u[4]; } pa, vb;
                #pragma unroll
                for (int d = 0; d < 4; ++d) {
                    pa.u[d] = cvt_pk_bf16(p[2*d],  p[2*d+1]);
                    vb.u[d] = cvt_pk_bf16(vt[2*d], vt[2*d+1]);
                }
                __builtin_amdgcn_s_setprio(1);
                accv = __builtin_amdgcn_mfma_f32_16x16x32_bf16(pa.v, vb.v, accv, 0, 0, 0);
                __builtin_amdgcn_s_setprio(0);
            }
        }

        // ---- bottom WAR fence: RAW barrier, no waitcnt drain ----
        __builtin_amdgcn_sched_barrier(0);
        __builtin_amdgcn_s_barrier();
        __builtin_amdgcn_sched_barrier(0);
        cur ^= 1;
    }

    // ---- final lrow reduction across the 4 lanes sharing each query ----
    lrow += __shfl_xor(lrow, 16);
    lrow += __shfl_xor(lrow, 32);

    // ---- write ----
    if (direct) {
        #pragma unroll
        for (int r = 0; r < 4; ++r) {
            float lqr = __shfl(lrow, lg*4 + r);
            out[(size_t)lk * N_PIX + qt0 + lg*4 + r] = accv[r] / lqr;
        }
    } else {
        #pragma unroll
        for (int r = 0; r < 4; ++r)
            macc[((size_t)(s*16 + lk)) * N_PIX + qt0 + lg*4 + r] = accv[r];
        if (lane < 16) {
            mbuf[(size_t)s * N_PIX + qt0 + lane] = mn;
            lbuf[(size_t)s * N_PIX + qt0 + lane] = lrow;
        }
    }
}

// ---------------------------------------------------------------------------
// Kernel 3: merge split-K partials (m in log2 units).
// ---------------------------------------------------------------------------
__global__ __launch_bounds__(256) void merge_kernel(
    const float* __restrict__ macc, const float* __restrict__ mbuf,
    const float* __restrict__ lbuf, float* __restrict__ out, int S)
{
    int tid = blockIdx.x * 256 + threadIdx.x;   // 0 .. 16*N_PIX-1
    int q = tid & (N_PIX - 1);
    int c = tid >> 14;
    float M = -INFINITY;
    for (int s = 0; s < S; ++s) M = fmaxf(M, mbuf[s*N_PIX + q]);
    float L = 0.f, O = 0.f;
    for (int s = 0; s < S; ++s) {
        float e = fexp2(mbuf[s*N_PIX + q] - M);
        L += lbuf[s*N_PIX + q] * e;
        O += macc[((size_t)(s*16 + c)) * N_PIX + q] * e;
    }
    out[tid] = O / L;
}

// ---------------------------------------------------------------------------
extern "C" void kernel_launch(void* const* d_in, const int* in_sizes, int n_in,
                              void* d_out, int out_size, void* d_ws, size_t ws_size,
                              hipStream_t stream) {
    const float* ego_cls   = (const float*)d_in[0];
    const float* ego_reg   = (const float*)d_in[1];
    const float* other_cls = (const float*)d_in[2];
    const float* other_reg = (const float*)d_in[3];
    const float* w1   = (const float*)d_in[4];
    const float* b1   = (const float*)d_in[5];
    const float* ln_g = (const float*)d_in[6];
    const float* ln_b = (const float*)d_in[7];
    const float* w2   = (const float*)d_in[8];
    const float* b2   = (const float*)d_in[9];

    unsigned short* qhi = (unsigned short*)d_ws;            // 4 MB each
    unsigned short* qlo = qhi + (size_t)N_PIX*EMB;
    unsigned short* khi = qlo + (size_t)N_PIX*EMB;
    unsigned short* klo = khi + (size_t)N_PIX*EMB;
    const size_t planes_bytes = (size_t)4 * N_PIX * EMB * 2;  // 16 MB

    auto need = [&](int S) { return planes_bytes + (size_t)S * N_PIX * 4 * 18; };
    int S = 1, direct = 1;
    if      (ws_size >= need(8)) { S = 8; direct = 0; }
    else if (ws_size >= need(4)) { S = 4; direct = 0; }
    else if (ws_size >= need(2)) { S = 2; direct = 0; }
    int TPS = NTILES / S;
    int XPS = 8 / S;

    float* macc = (float*)((char*)d_ws + planes_bytes);     // [S][16][N]
    float* mbuf = macc + (size_t)S * 16 * N_PIX;            // [S][N]
    float* lbuf = mbuf + (size_t)S * N_PIX;                 // [S][N]

    encode_kernel<<<2*N_PIX, 128, 0, stream>>>(
        ego_cls, ego_reg, other_cls, other_reg,
        w1, b1, ln_g, ln_b, w2, b2, qhi, qlo, khi, klo);

    // 128 query-blocks (128 queries each) x S slices
    attn_kernel<<<128*S, 512, 0, stream>>>(
        qhi, qlo, khi, klo, other_cls, other_reg,
        macc, mbuf, lbuf, (float*)d_out, S, TPS, XPS, direct);

    if (!direct)
        merge_kernel<<<(16*N_PIX)/256, 256, 0, stream>>>(
            macc, mbuf, lbuf, (float*)d_out, S);
}

// Round 19
// 253.166 us; speedup vs baseline: 1.8858x; 1.8858x over previous
//
#include <hip/hip_runtime.h>
#include <math.h>

#define N_PIX 16384
#define EMB 128
#define LN_EPS 1e-5f
#define INV_TEMP 10.0f
#define C2 14.4269504f          // INV_TEMP * log2(e): logits in log2 units
#define THR2 14.0f              // skip threshold (log2 units)
#define RTHR 8.0f               // cross-tier / defer-rescale threshold (log2 units)
#define BKT 32
#define NTILES (N_PIX / BKT)    // 512

typedef __attribute__((ext_vector_type(8))) short short8v;
typedef __attribute__((ext_vector_type(4))) float f32x4;

__device__ __forceinline__ float fexp2(float x) {
#if __has_builtin(__builtin_amdgcn_exp2f)
    return __builtin_amdgcn_exp2f(x);
#else
    float r; asm("v_exp_f32 %0, %1" : "=v"(r) : "v"(x)); return r;
#endif
}

__device__ __forceinline__ unsigned cvt_pk_bf16(float lo, float hi) {
    unsigned r;
    asm("v_cvt_pk_bf16_f32 %0, %1, %2" : "=v"(r) : "v"(lo), "v"(hi));
    return r;
}

__device__ __forceinline__ void split_bf16(float x, unsigned short& h, unsigned short& l) {
    union { float f; unsigned u; } a; a.f = x;
    h = (unsigned short)(a.u >> 16);
    union { unsigned u; float f; } b; b.u = a.u & 0xFFFF0000u;
    float r = x - b.f;
    union { float f; unsigned u; } c; c.f = r;
    unsigned ru = c.u + 0x7FFFu + ((c.u >> 16) & 1u);
    l = (unsigned short)(ru >> 16);
}

// ---------------------------------------------------------------------------
// Kernel 1: descriptor + MLP(6->128) + LN + MLP(128->128); emits bf16 hi/lo
// ---------------------------------------------------------------------------
__global__ __launch_bounds__(128) void encode_kernel(
    const float* __restrict__ ego_cls, const float* __restrict__ ego_reg,
    const float* __restrict__ other_cls, const float* __restrict__ other_reg,
    const float* __restrict__ w1, const float* __restrict__ b1,
    const float* __restrict__ ln_g, const float* __restrict__ ln_b,
    const float* __restrict__ w2, const float* __restrict__ b2,
    unsigned short* __restrict__ q_hi, unsigned short* __restrict__ q_lo,
    unsigned short* __restrict__ k_hi, unsigned short* __restrict__ k_lo)
{
    int r = blockIdx.x;
    const float* cls; const float* reg; unsigned short *ohi, *olo; int p;
    if (r < N_PIX) { cls = ego_cls;   reg = ego_reg;   ohi = q_hi; olo = q_lo; p = r; }
    else           { cls = other_cls; reg = other_reg; ohi = k_hi; olo = k_lo; p = r - N_PIX; }

    int j = threadIdx.x;

    float x0 = reg[3*N_PIX + p];
    float x1 = reg[4*N_PIX + p];
    float x2 = reg[5*N_PIX + p];
    float th = reg[6*N_PIX + p];
    float x3 = sinf(th);
    float x4 = cosf(th);
    float x5 = fmaxf(cls[p], cls[N_PIX + p]);

    float h = x0*w1[0*EMB+j] + x1*w1[1*EMB+j] + x2*w1[2*EMB+j]
            + x3*w1[3*EMB+j] + x4*w1[4*EMB+j] + x5*w1[5*EMB+j] + b1[j];
    h = fmaxf(h, 0.f);

    __shared__ float hn[EMB];
    __shared__ float red[4];

    float s = h, s2 = h*h;
    #pragma unroll
    for (int off = 32; off >= 1; off >>= 1) {
        s  += __shfl_xor(s,  off);
        s2 += __shfl_xor(s2, off);
    }
    int wid = j >> 6;
    if ((j & 63) == 0) { red[wid] = s; red[2+wid] = s2; }
    __syncthreads();
    float tot  = red[0] + red[1];
    float tot2 = red[2] + red[3];
    float mu  = tot * (1.f/EMB);
    float var = tot2 * (1.f/EMB) - mu*mu;
    float rstd = rsqrtf(var + LN_EPS);
    float hnj = (h - mu) * rstd * ln_g[j] + ln_b[j];
    hn[j] = hnj;
    __syncthreads();

    float acc = b2[j];
    #pragma unroll 8
    for (int k = 0; k < EMB; ++k)
        acc += hn[k] * w2[k*EMB + j];

    unsigned short hb, lb;
    split_bf16(acc, hb, lb);
    ohi[(size_t)p * EMB + j] = hb;
    olo[(size_t)p * EMB + j] = lb;
}

// ---------------------------------------------------------------------------
// Kernel 2: split-K flash attention, swapped-operand MFMA, 3-tier tile path:
//   skip (all queries < mtrack-14) | mid: hi*hi logits only (all < mn-8) |
//   cross: full split-precision. Staging + barrier structure FROZEN (R13/R16).
// R19 = exact revert to R17 (best verified state; R18's hi-only-LDS regressed
// 2.2x — cross-tier scattered lo-global reads are latency-serializing).
// ---------------------------------------------------------------------------
__device__ __forceinline__ void gl_lds16(const void* g, void* l) {
    __builtin_amdgcn_global_load_lds(
        (const __attribute__((address_space(1))) unsigned int*)(g),
        (__attribute__((address_space(3))) unsigned int*)(l), 16, 0, 0);
}

__global__ __launch_bounds__(512, 4) void attn_kernel(
    const unsigned short* __restrict__ Qhi, const unsigned short* __restrict__ Qlo,
    const unsigned short* __restrict__ Khi, const unsigned short* __restrict__ Klo,
    const float* __restrict__ other_cls, const float* __restrict__ other_reg,
    float* __restrict__ macc, float* __restrict__ mbuf, float* __restrict__ lbuf,
    float* __restrict__ out, int S, int TPS, int XPS, int direct)
{
    __shared__ char Ks[4 * 16384];   // [pair][sub][hi 8KB | lo 8KB]

    const int tid  = threadIdx.x;
    const int w    = tid >> 6, lane = tid & 63;   // w in 0..7
    const int lg   = lane >> 4, lk = lane & 15;

    // XCD-grouped bijective decode: slice pinned per XCD (K-slice L2-resident)
    const int b  = blockIdx.x;
    const int s  = (b & 7) / XPS;
    const int qb = (b >> 3) * XPS + (b & 7) % XPS;   // 0..127
    const int qt0 = qb * 128 + w * 16;
    const int t0  = s * TPS;
    const int HTPS = TPS >> 1;       // pairs per slice

    // ---- Q B-operand frags (k-map: k = kk*32 + lg*8 + e) ----
    short8v qbh[4], qbl[4];
    {
        const unsigned short* qh = Qhi + (size_t)(qt0 + lk) * EMB + lg*8;
        const unsigned short* ql = Qlo + (size_t)(qt0 + lk) * EMB + lg*8;
        #pragma unroll
        for (int kk = 0; kk < 4; ++kk) {
            qbh[kk] = *(const short8v*)(qh + kk*32);
            qbl[kk] = *(const short8v*)(ql + kk*32);
        }
    }

    // ---- staging precompute (waves 0-3 only; identical formulas to R6) ----
    const bool stager = (w < 4);
    int st_row[4], st_scol[4], st_pl[4], st_dst[4];
    #pragma unroll
    for (int i = 0; i < 4; ++i) {
        int ci = (w & 3)*4 + i;                 // 0..15 chunk-groups
        int cb = (ci & 7) * 64 + lane;          // chunk within plane
        int row  = cb >> 4;
        int colb = (cb & 15) << 4;
        st_pl[i]  = ci >> 3;                    // 0=hi, 1=lo
        st_row[i] = row;
        st_scol[i] = colb ^ ((row & 7) << 4);   // inverse-swizzled source col
        st_dst[i] = (ci >> 3) * 8192 + (ci & 7) * 1024;   // + lane*16 (HW)
    }

    // ---- A-frag read offsets (bytes in plane) ----
    int koff[4];
    #pragma unroll
    for (int kk = 0; kk < 4; ++kk)
        koff[kk] = (kk*64 + lg*16) ^ ((lk & 7) << 4);

    const float* vplane = (lk < 2) ? (other_cls + lk * N_PIX)
                                   : (other_reg + (lk - 2) * N_PIX);

    float mn = -INFINITY;      // softmax reference (log2 units), query-uniform
    float mtrack = -INFINITY;  // running query-uniform max for skip test
    float lrow = 0.f;          // PER-LANE partial (8 keys); reduced at end
    f32x4 accv = {0.f, 0.f, 0.f, 0.f};

    // prologue: stage pair 0 (tiles t0, t0+1) into buffers 0,1
    if (stager) {
        #pragma unroll
        for (int sub = 0; sub < 2; ++sub) {
            int kb0 = (t0 + sub) * BKT;
            #pragma unroll
            for (int i = 0; i < 4; ++i) {
                const unsigned short* src = st_pl[i] ? Klo : Khi;
                const char* g = (const char*)src + (((size_t)(kb0 + st_row[i])) << 8) + st_scol[i];
                gl_lds16(g, Ks + sub * 16384 + st_dst[i]);
            }
        }
    }

    int cur = 0;
    for (int it = 0; it < HTPS; ++it) {
        if (stager) {
            if (it + 1 < HTPS) {
                #pragma unroll
                for (int sub = 0; sub < 2; ++sub) {
                    int kn0 = (t0 + 2*(it+1) + sub) * BKT;
                    char* dstb = Ks + ((cur ^ 1) * 2 + sub) * 16384;
                    #pragma unroll
                    for (int i = 0; i < 4; ++i) {
                        const unsigned short* src = st_pl[i] ? Klo : Khi;
                        const char* g = (const char*)src + (((size_t)(kn0 + st_row[i])) << 8) + st_scol[i];
                        gl_lds16(g, dstb + st_dst[i]);
                    }
                }
                asm volatile("s_waitcnt vmcnt(8)" ::: "memory");  // only next-pair stage outstanding
            } else {
                asm volatile("s_waitcnt vmcnt(0)" ::: "memory");
            }
        }
        __builtin_amdgcn_sched_barrier(0);
        __builtin_amdgcn_s_barrier();
        __builtin_amdgcn_sched_barrier(0);

        #pragma unroll
        for (int sub = 0; sub < 2; ++sub) {
            const int kb0 = (t0 + 2*it + sub) * BKT;
            const char* Bh = Ks + (cur * 2 + sub) * 16384;
            const char* Bl = Bh + 8192;
            const int rowb = lk * 256;

            // ---- hi*hi pass: S[key][query]; keep hi A-frags in regs ----
            short8v ah0r[4], ah1r[4];
            f32x4 S0 = {0,0,0,0}, S1 = {0,0,0,0};
            #pragma unroll
            for (int kk = 0; kk < 4; ++kk) {
                ah0r[kk] = *(const short8v*)(Bh + rowb + koff[kk]);
                ah1r[kk] = *(const short8v*)(Bh + 4096 + rowb + koff[kk]);
            }
            __builtin_amdgcn_s_setprio(1);
            #pragma unroll
            for (int kk = 0; kk < 4; ++kk) {
                S0 = __builtin_amdgcn_mfma_f32_16x16x32_bf16(ah0r[kk], qbh[kk], S0, 0, 0, 0);
                S1 = __builtin_amdgcn_mfma_f32_16x16x32_bf16(ah1r[kk], qbh[kk], S1, 0, 0, 0);
            }
            __builtin_amdgcn_s_setprio(0);

            // ---- shuffle-free skip test (exact: __any spans all lanes) ----
            float mtl = fmaxf(fmaxf(fmaxf(S0[0], S0[1]), fmaxf(S0[2], S0[3])),
                              fmaxf(fmaxf(S1[0], S1[1]), fmaxf(S1[2], S1[3])));
            float mtl2 = mtl * C2;
            if (__any(mtl2 > mtrack - THR2)) {
                // V loads (taken tiles only; use-drained before barrier)
                float vt[8];
                #pragma unroll
                for (int e = 0; e < 8; ++e)
                    vt[e] = vplane[kb0 + 16*(e>>2) + lg*4 + (e&3)];

                // ---- tier test (shuffle-free, exact): cross-precision needed
                //      only if some query's tile max is within RTHR of its mn ----
                float sc = 1.f;
                if (__any(mtl2 > mn - RTHR)) {
                    // query-uniform tile max (2 shuffles; cross tier only)
                    float mt = fmaxf(mtl, __shfl_xor(mtl, 16));
                    mt = fmaxf(mt, __shfl_xor(mt, 32));
                    float mt2 = mt * C2;
                    mtrack = fmaxf(mtrack, mt2);

                    // ---- cross terms: + kh*ql + kl*qh (hi frags from regs) ----
                    __builtin_amdgcn_s_setprio(1);
                    #pragma unroll
                    for (int kk = 0; kk < 4; ++kk) {
                        short8v al0 = *(const short8v*)(Bl + rowb + koff[kk]);
                        short8v al1 = *(const short8v*)(Bl + 4096 + rowb + koff[kk]);
                        S0 = __builtin_amdgcn_mfma_f32_16x16x32_bf16(ah0r[kk], qbl[kk], S0, 0, 0, 0);
                        S1 = __builtin_amdgcn_mfma_f32_16x16x32_bf16(ah1r[kk], qbl[kk], S1, 0, 0, 0);
                        S0 = __builtin_amdgcn_mfma_f32_16x16x32_bf16(al0, qbh[kk], S0, 0, 0, 0);
                        S1 = __builtin_amdgcn_mfma_f32_16x16x32_bf16(al1, qbh[kk], S1, 0, 0, 0);
                    }
                    __builtin_amdgcn_s_setprio(0);

                    // ---- defer-rescale (mn query-uniform) ----
                    if (__any(mt2 > mn + RTHR)) {
                        float mnn = fmaxf(mn, mt2);
                        sc = fexp2(mn - mnn);           // first tile: exp2(-inf)=0
                        mn = mnn;
                        #pragma unroll
                        for (int r = 0; r < 4; ++r)
                            accv[r] *= __shfl(sc, lg*4 + r);
                    }
                }
                // mid tier: hi*hi logits only; all weights < 2^-RTHR -> error ~0

                // per-lane partial row-sum; lrow reduced across lanes at END
                float p[8]; float rs = 0.f;
                #pragma unroll
                for (int r = 0; r < 4; ++r) { p[r]   = fexp2(fmaf(S0[r], C2, -mn)); rs += p[r];   }
                #pragma unroll
                for (int r = 0; r < 4; ++r) { p[4+r] = fexp2(fmaf(S1[r], C2, -mn)); rs += p[4+r]; }
                lrow = lrow * sc + rs;

                // ---- PV: one MFMA; key-map pi(l,e)=16*(e>>2)+lg*4+(e&3) ----
                union { short8v v; unsigned u[4]; } pa, vb;
                #pragma unroll
                for (int d = 0; d < 4; ++d) {
                    pa.u[d] = cvt_pk_bf16(p[2*d],  p[2*d+1]);
                    vb.u[d] = cvt_pk_bf16(vt[2*d], vt[2*d+1]);
                }
                __builtin_amdgcn_s_setprio(1);
                accv = __builtin_amdgcn_mfma_f32_16x16x32_bf16(pa.v, vb.v, accv, 0, 0, 0);
                __builtin_amdgcn_s_setprio(0);
            }
        }

        // ---- bottom WAR fence: RAW barrier, no waitcnt drain (R16) ----
        __builtin_amdgcn_sched_barrier(0);
        __builtin_amdgcn_s_barrier();
        __builtin_amdgcn_sched_barrier(0);
        cur ^= 1;
    }

    // ---- final lrow reduction across the 4 lanes sharing each query ----
    lrow += __shfl_xor(lrow, 16);
    lrow += __shfl_xor(lrow, 32);

    // ---- write ----
    if (direct) {
        #pragma unroll
        for (int r = 0; r < 4; ++r) {
            float lqr = __shfl(lrow, lg*4 + r);
            out[(size_t)lk * N_PIX + qt0 + lg*4 + r] = accv[r] / lqr;
        }
    } else {
        #pragma unroll
        for (int r = 0; r < 4; ++r)
            macc[((size_t)(s*16 + lk)) * N_PIX + qt0 + lg*4 + r] = accv[r];
        if (lane < 16) {
            mbuf[(size_t)s * N_PIX + qt0 + lane] = mn;
            lbuf[(size_t)s * N_PIX + qt0 + lane] = lrow;
        }
    }
}

// ---------------------------------------------------------------------------
// Kernel 3: merge split-K partials (m in log2 units).
// ---------------------------------------------------------------------------
__global__ __launch_bounds__(256) void merge_kernel(
    const float* __restrict__ macc, const float* __restrict__ mbuf,
    const float* __restrict__ lbuf, float* __restrict__ out, int S)
{
    int tid = blockIdx.x * 256 + threadIdx.x;   // 0 .. 16*N_PIX-1
    int q = tid & (N_PIX - 1);
    int c = tid >> 14;
    float M = -INFINITY;
    for (int s = 0; s < S; ++s) M = fmaxf(M, mbuf[s*N_PIX + q]);
    float L = 0.f, O = 0.f;
    for (int s = 0; s < S; ++s) {
        float e = fexp2(mbuf[s*N_PIX + q] - M);
        L += lbuf[s*N_PIX + q] * e;
        O += macc[((size_t)(s*16 + c)) * N_PIX + q] * e;
    }
    out[tid] = O / L;
}

// ---------------------------------------------------------------------------
extern "C" void kernel_launch(void* const* d_in, const int* in_sizes, int n_in,
                              void* d_out, int out_size, void* d_ws, size_t ws_size,
                              hipStream_t stream) {
    const float* ego_cls   = (const float*)d_in[0];
    const float* ego_reg   = (const float*)d_in[1];
    const float* other_cls = (const float*)d_in[2];
    const float* other_reg = (const float*)d_in[3];
    const float* w1   = (const float*)d_in[4];
    const float* b1   = (const float*)d_in[5];
    const float* ln_g = (const float*)d_in[6];
    const float* ln_b = (const float*)d_in[7];
    const float* w2   = (const float*)d_in[8];
    const float* b2   = (const float*)d_in[9];

    unsigned short* qhi = (unsigned short*)d_ws;            // 4 MB each
    unsigned short* qlo = qhi + (size_t)N_PIX*EMB;
    unsigned short* khi = qlo + (size_t)N_PIX*EMB;
    unsigned short* klo = khi + (size_t)N_PIX*EMB;
    const size_t planes_bytes = (size_t)4 * N_PIX * EMB * 2;  // 16 MB

    auto need = [&](int S) { return planes_bytes + (size_t)S * N_PIX * 4 * 18; };
    int S = 1, direct = 1;
    if      (ws_size >= need(8)) { S = 8; direct = 0; }
    else if (ws_size >= need(4)) { S = 4; direct = 0; }
    else if (ws_size >= need(2)) { S = 2; direct = 0; }
    int TPS = NTILES / S;
    int XPS = 8 / S;

    float* macc = (float*)((char*)d_ws + planes_bytes);     // [S][16][N]
    float* mbuf = macc + (size_t)S * 16 * N_PIX;            // [S][N]
    float* lbuf = mbuf + (size_t)S * N_PIX;                 // [S][N]

    encode_kernel<<<2*N_PIX, 128, 0, stream>>>(
        ego_cls, ego_reg, other_cls, other_reg,
        w1, b1, ln_g, ln_b, w2, b2, qhi, qlo, khi, klo);

    // 128 query-blocks (128 queries each) x S slices
    attn_kernel<<<128*S, 512, 0, stream>>>(
        qhi, qlo, khi, klo, other_cls, other_reg,
        macc, mbuf, lbuf, (float*)d_out, S, TPS, XPS, direct);

    if (!direct)
        merge_kernel<<<(16*N_PIX)/256, 256, 0, stream>>>(
            macc, mbuf, lbuf, (float*)d_out, S);
}